// Round 6
// baseline (185.621 us; speedup 1.0000x reference)
//
#include <hip/hip_runtime.h>

// PCLLoss: C=256 classes, N=64 samples/class, D=1024.
// loss = mean_i [ sum_c ( log(eps + S_{i,c}) - pred[i,c] ) ]
// pred = Mv Mv^T, true = Mt Mt^T, Mv/Mt = per-class means of L2-normalized
// rows; S_{i,c} = sum_j exp(pred[i,j]) over j ranked at-or-after c in a
// stable descending sort of true[i,:]  (computed sort-free via an O(C) scan).
//
// R6: k1 as a pure stream. Global loads feed only an LDS store + local fmac
// (regs die immediately -> no remat cliff); scale-phase reads LDS, not L1/L2
// (single global touch per byte); next round's loads prefetched BEFORE the
// butterfly so VMEM stays in flight across shuffle+barrier. Double-buffered
// 32 KB LDS, 1 barrier/round. This disambiguates: R2-R5 k1 variants all
// pinned at 47-51 us (~2.7 TB/s read) -- if this lands there too, the
// pure-read MLP wall is confirmed and k1 is at its floor.

#define CC 256
#define NN 64
#define DD 1024
#define PARTS 4
#define TK 128   // K-slice for gram split-K

// ---------------- K1: normalize + partial class sums ------------------
// grid = 2*CC*PARTS = 2048 blocks x 256 thr. Block (t,c,p): 16 rows in 4
// rounds of 4; wave w streams row rnd*4+w into LDS while computing its
// sum-of-squares; all threads then scale-accumulate from LDS at own cols.
__global__ __launch_bounds__(256) void k1_partial(
    const float* __restrict__ emb, const float* __restrict__ feat,
    float* __restrict__ parts /* [2][CC][PARTS][DD] */, float* __restrict__ out)
{
    if (blockIdx.x == 0 && threadIdx.x == 0) out[0] = 0.f;  // for k3b atomics

    int b = blockIdx.x;
    int t = b >> 10;              // tensor
    int c = (b >> 2) & 255;       // class
    int p = b & 3;                // part (16 rows)
    const float* src = (t == 0 ? emb : feat) + ((size_t)c * NN + p * 16) * DD;
    int wave = threadIdx.x >> 6, lane = threadIdx.x & 63;
    int col = threadIdx.x * 4;    // this thread's 4 output columns

    __shared__ float sv[2][4][DD];   // 32 KB row double-buffer
    __shared__ float sinv[2][4];

    float4 v[4], vn[4];
    {
        const float* r0 = src + (size_t)wave * DD;
        #pragma unroll
        for (int k = 0; k < 4; ++k)
            v[k] = *(const float4*)(r0 + k * 256 + lane * 4);
    }

    float4 acc = make_float4(0.f, 0.f, 0.f, 0.f);

    #pragma unroll
    for (int rnd = 0; rnd < 4; ++rnd) {
        int buf = rnd & 1;
        // stage this round's row to LDS; regs also feed local ss, then die
        #pragma unroll
        for (int k = 0; k < 4; ++k)
            *(float4*)&sv[buf][wave][k * 256 + lane * 4] = v[k];
        float ss = 0.f;
        #pragma unroll
        for (int k = 0; k < 4; ++k)
            ss += v[k].x * v[k].x + v[k].y * v[k].y +
                  v[k].z * v[k].z + v[k].w * v[k].w;

        // prefetch next round's row BEFORE the butterfly: loads stay in
        // flight across the shuffle chain and the barrier
        if (rnd < 3) {
            const float* rn = src + (size_t)((rnd + 1) * 4 + wave) * DD;
            #pragma unroll
            for (int k = 0; k < 4; ++k)
                vn[k] = *(const float4*)(rn + k * 256 + lane * 4);
        }

        #pragma unroll
        for (int m = 32; m >= 1; m >>= 1)
            ss += __shfl_xor(ss, m, 64);
        if (lane == 0)
            sinv[buf][wave] = 1.0f / fmaxf(sqrtf(ss), 1e-12f);  // F.normalize eps
        __syncthreads();

        // consume from LDS (not global): 4 b128 reads + broadcast scalars
        float i0 = sinv[buf][0], i1 = sinv[buf][1];
        float i2 = sinv[buf][2], i3 = sinv[buf][3];
        float4 u0 = *(float4*)&sv[buf][0][col];
        float4 u1 = *(float4*)&sv[buf][1][col];
        float4 u2 = *(float4*)&sv[buf][2][col];
        float4 u3 = *(float4*)&sv[buf][3][col];
        acc.x += u0.x * i0 + u1.x * i1 + u2.x * i2 + u3.x * i3;
        acc.y += u0.y * i0 + u1.y * i1 + u2.y * i2 + u3.y * i3;
        acc.z += u0.z * i0 + u1.z * i1 + u2.z * i2 + u3.z * i3;
        acc.w += u0.w * i0 + u1.w * i1 + u2.w * i2 + u3.w * i3;

        if (rnd < 3) {
            #pragma unroll
            for (int k = 0; k < 4; ++k) v[k] = vn[k];
        }
    }

    *(float4*)(parts + (((size_t)t * CC + c) * PARTS + p) * DD + col) = acc;
}

// ---------------- K3a: split-K tiled Gram partials (k2 fused) ---------
// grid = 2 tensors * 16 tiles(64x64) * 8 K-splits = 256 blocks, 256 thr.
// Stages directly from parts: mean = (sum of 4 parts) / N at load time.
__global__ __launch_bounds__(256) void k3a_gram(
    const float* __restrict__ parts, float* __restrict__ gpart /* [2][8][CC][CC] */)
{
    __shared__ float As[64][132];
    __shared__ float Bs[TK][68];

    int b = blockIdx.x;
    int t = b >> 7;
    int r = b & 127;
    int ks = r >> 4;
    int ti = (r >> 2) & 3, tj = r & 3;
    int i0 = ti * 64, j0 = tj * 64, k0 = ks * TK;
    const float invN = 1.0f / (float)NN;

    for (int f = threadIdx.x; f < 64 * 32; f += 256) {
        int row = f >> 5, c4 = f & 31;
        const float* P = parts + ((size_t)(t * CC + i0 + row) * PARTS) * DD + k0 + c4 * 4;
        float4 v0 = *(const float4*)(P);
        float4 v1 = *(const float4*)(P + DD);
        float4 v2 = *(const float4*)(P + 2 * DD);
        float4 v3 = *(const float4*)(P + 3 * DD);
        float4 v = make_float4((v0.x + v1.x + v2.x + v3.x) * invN,
                               (v0.y + v1.y + v2.y + v3.y) * invN,
                               (v0.z + v1.z + v2.z + v3.z) * invN,
                               (v0.w + v1.w + v2.w + v3.w) * invN);
        *(float4*)&As[row][c4 * 4] = v;
    }
    for (int f = threadIdx.x; f < 64 * 32; f += 256) {
        int row = f >> 5, c4 = f & 31;
        const float* P = parts + ((size_t)(t * CC + j0 + row) * PARTS) * DD + k0 + c4 * 4;
        float4 v0 = *(const float4*)(P);
        float4 v1 = *(const float4*)(P + DD);
        float4 v2 = *(const float4*)(P + 2 * DD);
        float4 v3 = *(const float4*)(P + 3 * DD);
        Bs[c4 * 4 + 0][row] = (v0.x + v1.x + v2.x + v3.x) * invN;
        Bs[c4 * 4 + 1][row] = (v0.y + v1.y + v2.y + v3.y) * invN;
        Bs[c4 * 4 + 2][row] = (v0.z + v1.z + v2.z + v3.z) * invN;
        Bs[c4 * 4 + 3][row] = (v0.w + v1.w + v2.w + v3.w) * invN;
    }
    __syncthreads();

    int tr = threadIdx.x >> 4, tc = threadIdx.x & 15;
    float acc[4][4] = {};
    #pragma unroll 4
    for (int kk = 0; kk < TK; kk += 4) {
        float4 a[4], bb[4];
        #pragma unroll
        for (int q = 0; q < 4; ++q) a[q] = *(float4*)&As[tr * 4 + q][kk];
        #pragma unroll
        for (int kq = 0; kq < 4; ++kq) bb[kq] = *(float4*)&Bs[kk + kq][tc * 4];
        #pragma unroll
        for (int q = 0; q < 4; ++q) {
            acc[q][0] += a[q].x * bb[0].x + a[q].y * bb[1].x + a[q].z * bb[2].x + a[q].w * bb[3].x;
            acc[q][1] += a[q].x * bb[0].y + a[q].y * bb[1].y + a[q].z * bb[2].y + a[q].w * bb[3].y;
            acc[q][2] += a[q].x * bb[0].z + a[q].y * bb[1].z + a[q].z * bb[2].z + a[q].w * bb[3].z;
            acc[q][3] += a[q].x * bb[0].w + a[q].y * bb[1].w + a[q].z * bb[2].w + a[q].w * bb[3].w;
        }
    }

    float* G = gpart + (((size_t)(t * 8 + ks) * CC) + i0 + tr * 4) * CC + j0 + tc * 4;
    #pragma unroll
    for (int q = 0; q < 4; ++q)
        *(float4*)(G + (size_t)q * CC) =
            make_float4(acc[q][0], acc[q][1], acc[q][2], acc[q][3]);
}

// ---------------- K3b: reduce partials + ListMLE + final mean ---------
// grid = CC blocks; one atomicAdd per block into out (zeroed by k1).
__global__ __launch_bounds__(256) void k3b_listmle(
    const float* __restrict__ gpart, float* __restrict__ out)
{
    int i = blockIdx.x, c = threadIdx.x;
    float dp = 0.f, dt = 0.f;
    #pragma unroll
    for (int ks = 0; ks < 8; ++ks) {
        dp += gpart[((size_t)ks * CC + i) * CC + c];
        dt += gpart[((size_t)(8 + ks) * CC + i) * CC + c];
    }

    __shared__ float s_true[CC];
    __shared__ float s_pexp[CC];
    s_true[c] = dt;
    s_pexp[c] = expf(dp);
    __syncthreads();

    // S = sum exp(pred_j) over j ranked at-or-after c (stable desc by true)
    float S = 0.f;
    for (int j = 0; j < CC; ++j) {
        float tj = s_true[j];
        bool take = (tj < dt) || (tj == dt && j >= c);
        S += take ? s_pexp[j] : 0.f;
    }
    float contrib = logf(S + 1e-10f) - dp;

    #pragma unroll
    for (int m = 32; m >= 1; m >>= 1)
        contrib += __shfl_xor(contrib, m, 64);
    __shared__ float s_red[4];
    if ((c & 63) == 0) s_red[c >> 6] = contrib;
    __syncthreads();
    if (c == 0)
        atomicAdd(out, (s_red[0] + s_red[1] + s_red[2] + s_red[3]) * (1.0f / (float)CC));
}

extern "C" void kernel_launch(void* const* d_in, const int* in_sizes, int n_in,
                              void* d_out, int out_size, void* d_ws, size_t ws_size,
                              hipStream_t stream) {
    const float* emb  = (const float*)d_in[0];
    const float* feat = (const float*)d_in[1];
    float* ws = (float*)d_ws;
    float* parts = ws;                                  // 2*CC*PARTS*DD = 8 MiB
    float* gpart = parts + (size_t)2 * CC * PARTS * DD; // 2*8*CC*CC = 4 MiB

    k1_partial <<<2 * CC * PARTS, 256, 0, stream>>>(emb, feat, parts, (float*)d_out);
    k3a_gram   <<<256, 256, 0, stream>>>(parts, gpart);
    k3b_listmle<<<CC, 256, 0, stream>>>(gpart, (float*)d_out);
}

// Round 7
// 183.892 us; speedup vs baseline: 1.0094x; 1.0094x over previous
//
#include <hip/hip_runtime.h>

// PCLLoss: C=256 classes, N=64 samples/class, D=1024.
// loss = mean_i [ sum_c ( log(eps + S_{i,c}) - pred[i,c] ) ]
// pred = Mv Mv^T, true = Mt Mt^T, Mv/Mt = per-class means of L2-normalized
// rows; S_{i,c} = sum_j exp(pred[i,j]) over j ranked at-or-after c in a
// stable descending sort of true[i,:]  (computed sort-free via an O(C) scan).
//
// R7: k1 staging via global_load_lds (async DMA, register-free). R2-R6's
// five k1 variants all pinned at ~2.7 TB/s read: VGPR-destination loads cap
// outstanding bytes at ~8 float4/wave -> ~4 KB/CU in flight -> 4KB/375ns
// = 2.7 TB/s. DMA staging has no register payload: 64 instr/block all in
// flight (64 KB/block, ~128 KB/CU at 2 blocks/CU) >> 22 KB BW*latency
// product. Norms + accumulate then read LDS only; one global touch/byte.

#define CC 256
#define NN 64
#define DD 1024
#define PARTS 4
#define TK 128   // K-slice for gram split-K

__device__ __forceinline__ void async_load16(const float* g, float* l) {
    __builtin_amdgcn_global_load_lds(
        (const __attribute__((address_space(1))) void*)g,
        (__attribute__((address_space(3))) void*)l,
        16, 0, 0);  // 16 B/lane: lane i -> lds_base + i*16
}

// ---------------- K1: DMA-staged normalize + partial class sums -------
// grid = 2*CC*PARTS = 2048 blocks x 256 thr. Block (t,c,p): stage 16 rows
// (64 KB) via global_load_lds; norms from LDS (wave w: rows r*4+w); then
// every thread accumulates its 4 columns over all 16 rows from LDS.
__global__ __launch_bounds__(256) void k1_partial(
    const float* __restrict__ emb, const float* __restrict__ feat,
    float* __restrict__ parts /* [2][CC][PARTS][DD] */, float* __restrict__ out)
{
    if (blockIdx.x == 0 && threadIdx.x == 0) out[0] = 0.f;  // for k3b atomics

    int b = blockIdx.x;
    int t = b >> 10;              // tensor
    int c = (b >> 2) & 255;       // class
    int p = b & 3;                // part (16 rows)
    const float* src = (t == 0 ? emb : feat) + ((size_t)c * NN + p * 16) * DD;
    int wave = threadIdx.x >> 6, lane = threadIdx.x & 63;
    int col = threadIdx.x * 4;    // this thread's 4 output columns

    __shared__ float stage[16][DD];   // 64 KB -> 2 blocks/CU
    __shared__ float sinv[16];

    // issue all 16 DMA instructions per wave back-to-back (no reg payload)
    #pragma unroll
    for (int j = 0; j < 4; ++j) {
        int row = wave * 4 + j;
        const float* g = src + (size_t)row * DD + lane * 4;
        #pragma unroll
        for (int k = 0; k < 4; ++k)
            async_load16(g + k * 256, &stage[row][k * 256]);
    }
    __syncthreads();  // drains vmcnt(0) + barrier

    // norm phase: wave w handles rows r*4+w, r=0..3 (LDS reads only)
    #pragma unroll
    for (int r = 0; r < 4; ++r) {
        int row = r * 4 + wave;
        float4 v0 = *(float4*)&stage[row][0 * 256 + lane * 4];
        float4 v1 = *(float4*)&stage[row][1 * 256 + lane * 4];
        float4 v2 = *(float4*)&stage[row][2 * 256 + lane * 4];
        float4 v3 = *(float4*)&stage[row][3 * 256 + lane * 4];
        float ss = v0.x * v0.x + v0.y * v0.y + v0.z * v0.z + v0.w * v0.w
                 + v1.x * v1.x + v1.y * v1.y + v1.z * v1.z + v1.w * v1.w
                 + v2.x * v2.x + v2.y * v2.y + v2.z * v2.z + v2.w * v2.w
                 + v3.x * v3.x + v3.y * v3.y + v3.z * v3.z + v3.w * v3.w;
        #pragma unroll
        for (int m = 32; m >= 1; m >>= 1)
            ss += __shfl_xor(ss, m, 64);
        if (lane == 0)
            sinv[row] = 1.0f / fmaxf(sqrtf(ss), 1e-12f);  // F.normalize eps
    }
    __syncthreads();

    // accumulate: own columns across all 16 rows (LDS b128 + broadcast)
    float4 acc = make_float4(0.f, 0.f, 0.f, 0.f);
    #pragma unroll
    for (int row = 0; row < 16; ++row) {
        float iv = sinv[row];
        float4 u = *(float4*)&stage[row][col];
        acc.x += u.x * iv; acc.y += u.y * iv;
        acc.z += u.z * iv; acc.w += u.w * iv;
    }
    *(float4*)(parts + (((size_t)t * CC + c) * PARTS + p) * DD + col) = acc;
}

// ---------------- K3a: split-K tiled Gram partials (k2 fused) ---------
// grid = 2 tensors * 16 tiles(64x64) * 8 K-splits = 256 blocks, 256 thr.
// Stages directly from parts: mean = (sum of 4 parts) / N at load time.
__global__ __launch_bounds__(256) void k3a_gram(
    const float* __restrict__ parts, float* __restrict__ gpart /* [2][8][CC][CC] */)
{
    __shared__ float As[64][132];
    __shared__ float Bs[TK][68];

    int b = blockIdx.x;
    int t = b >> 7;
    int r = b & 127;
    int ks = r >> 4;
    int ti = (r >> 2) & 3, tj = r & 3;
    int i0 = ti * 64, j0 = tj * 64, k0 = ks * TK;
    const float invN = 1.0f / (float)NN;

    for (int f = threadIdx.x; f < 64 * 32; f += 256) {
        int row = f >> 5, c4 = f & 31;
        const float* P = parts + ((size_t)(t * CC + i0 + row) * PARTS) * DD + k0 + c4 * 4;
        float4 v0 = *(const float4*)(P);
        float4 v1 = *(const float4*)(P + DD);
        float4 v2 = *(const float4*)(P + 2 * DD);
        float4 v3 = *(const float4*)(P + 3 * DD);
        float4 v = make_float4((v0.x + v1.x + v2.x + v3.x) * invN,
                               (v0.y + v1.y + v2.y + v3.y) * invN,
                               (v0.z + v1.z + v2.z + v3.z) * invN,
                               (v0.w + v1.w + v2.w + v3.w) * invN);
        *(float4*)&As[row][c4 * 4] = v;
    }
    for (int f = threadIdx.x; f < 64 * 32; f += 256) {
        int row = f >> 5, c4 = f & 31;
        const float* P = parts + ((size_t)(t * CC + j0 + row) * PARTS) * DD + k0 + c4 * 4;
        float4 v0 = *(const float4*)(P);
        float4 v1 = *(const float4*)(P + DD);
        float4 v2 = *(const float4*)(P + 2 * DD);
        float4 v3 = *(const float4*)(P + 3 * DD);
        Bs[c4 * 4 + 0][row] = (v0.x + v1.x + v2.x + v3.x) * invN;
        Bs[c4 * 4 + 1][row] = (v0.y + v1.y + v2.y + v3.y) * invN;
        Bs[c4 * 4 + 2][row] = (v0.z + v1.z + v2.z + v3.z) * invN;
        Bs[c4 * 4 + 3][row] = (v0.w + v1.w + v2.w + v3.w) * invN;
    }
    __syncthreads();

    int tr = threadIdx.x >> 4, tc = threadIdx.x & 15;
    float acc[4][4] = {};
    #pragma unroll 4
    for (int kk = 0; kk < TK; kk += 4) {
        float4 a[4], bb[4];
        #pragma unroll
        for (int q = 0; q < 4; ++q) a[q] = *(float4*)&As[tr * 4 + q][kk];
        #pragma unroll
        for (int kq = 0; kq < 4; ++kq) bb[kq] = *(float4*)&Bs[kk + kq][tc * 4];
        #pragma unroll
        for (int q = 0; q < 4; ++q) {
            acc[q][0] += a[q].x * bb[0].x + a[q].y * bb[1].x + a[q].z * bb[2].x + a[q].w * bb[3].x;
            acc[q][1] += a[q].x * bb[0].y + a[q].y * bb[1].y + a[q].z * bb[2].y + a[q].w * bb[3].y;
            acc[q][2] += a[q].x * bb[0].z + a[q].y * bb[1].z + a[q].z * bb[2].z + a[q].w * bb[3].z;
            acc[q][3] += a[q].x * bb[0].w + a[q].y * bb[1].w + a[q].z * bb[2].w + a[q].w * bb[3].w;
        }
    }

    float* G = gpart + (((size_t)(t * 8 + ks) * CC) + i0 + tr * 4) * CC + j0 + tc * 4;
    #pragma unroll
    for (int q = 0; q < 4; ++q)
        *(float4*)(G + (size_t)q * CC) =
            make_float4(acc[q][0], acc[q][1], acc[q][2], acc[q][3]);
}

// ---------------- K3b: reduce partials + ListMLE + final mean ---------
// grid = CC blocks; one atomicAdd per block into out (zeroed by k1).
__global__ __launch_bounds__(256) void k3b_listmle(
    const float* __restrict__ gpart, float* __restrict__ out)
{
    int i = blockIdx.x, c = threadIdx.x;
    float dp = 0.f, dt = 0.f;
    #pragma unroll
    for (int ks = 0; ks < 8; ++ks) {
        dp += gpart[((size_t)ks * CC + i) * CC + c];
        dt += gpart[((size_t)(8 + ks) * CC + i) * CC + c];
    }

    __shared__ float s_true[CC];
    __shared__ float s_pexp[CC];
    s_true[c] = dt;
    s_pexp[c] = expf(dp);
    __syncthreads();

    // S = sum exp(pred_j) over j ranked at-or-after c (stable desc by true)
    float S = 0.f;
    for (int j = 0; j < CC; ++j) {
        float tj = s_true[j];
        bool take = (tj < dt) || (tj == dt && j >= c);
        S += take ? s_pexp[j] : 0.f;
    }
    float contrib = logf(S + 1e-10f) - dp;

    #pragma unroll
    for (int m = 32; m >= 1; m >>= 1)
        contrib += __shfl_xor(contrib, m, 64);
    __shared__ float s_red[4];
    if ((c & 63) == 0) s_red[c >> 6] = contrib;
    __syncthreads();
    if (c == 0)
        atomicAdd(out, (s_red[0] + s_red[1] + s_red[2] + s_red[3]) * (1.0f / (float)CC));
}

extern "C" void kernel_launch(void* const* d_in, const int* in_sizes, int n_in,
                              void* d_out, int out_size, void* d_ws, size_t ws_size,
                              hipStream_t stream) {
    const float* emb  = (const float*)d_in[0];
    const float* feat = (const float*)d_in[1];
    float* ws = (float*)d_ws;
    float* parts = ws;                                  // 2*CC*PARTS*DD = 8 MiB
    float* gpart = parts + (size_t)2 * CC * PARTS * DD; // 2*8*CC*CC = 4 MiB

    k1_partial <<<2 * CC * PARTS, 256, 0, stream>>>(emb, feat, parts, (float*)d_out);
    k3a_gram   <<<256, 256, 0, stream>>>(parts, gpart);
    k3b_listmle<<<CC, 256, 0, stream>>>(gpart, (float*)d_out);
}

// Round 8
// 177.427 us; speedup vs baseline: 1.0462x; 1.0364x over previous
//
#include <hip/hip_runtime.h>

// PCLLoss: C=256 classes, N=64 samples/class, D=1024.
// loss = mean_i [ sum_c ( log(eps + S_{i,c}) - pred[i,c] ) ]
// pred = Mv Mv^T, true = Mt Mt^T, Mv/Mt = per-class means of L2-normalized
// rows; S_{i,c} = sum_j exp(pred[i,j]) over j ranked at-or-after c in a
// stable descending sort of true[i,:]  (computed sort-free via an O(C) scan).
//
// R8: k1 = R6 structure + NONTEMPORAL loads (single variable). Six k1
// variants (reg loads at 18-63% occ, LDS staging, prefetch, async DMA)
// all pinned at 46-51 us regardless of issue mechanism / occupancy /
// FETCH mix -> in-flight-bytes model dead. Remaining suspect: L2
// allocation churn on a zero-reuse 134 MB stream (evicts + writes back
// the restore's dirty lines). nt loads skip L2 allocate; write-only
// fills (streaming) hit 6.6 TB/s while allocating reads pin at ~2.8.

#define CC 256
#define NN 64
#define DD 1024
#define PARTS 4
#define TK 128   // K-slice for gram split-K

typedef float v4f __attribute__((ext_vector_type(4)));
__device__ __forceinline__ float4 ntload4(const float* p) {
    v4f v = __builtin_nontemporal_load((const v4f*)p);
    return make_float4(v.x, v.y, v.z, v.w);
}

// ---------------- K1: normalize + partial class sums ------------------
// grid = 2*CC*PARTS = 2048 blocks x 256 thr. Block (t,c,p): 16 rows in 4
// rounds of 4; wave w streams row rnd*4+w into LDS while computing its
// sum-of-squares; all threads then scale-accumulate from LDS at own cols.
__global__ __launch_bounds__(256) void k1_partial(
    const float* __restrict__ emb, const float* __restrict__ feat,
    float* __restrict__ parts /* [2][CC][PARTS][DD] */, float* __restrict__ out)
{
    if (blockIdx.x == 0 && threadIdx.x == 0) out[0] = 0.f;  // for k3b atomics

    int b = blockIdx.x;
    int t = b >> 10;              // tensor
    int c = (b >> 2) & 255;       // class
    int p = b & 3;                // part (16 rows)
    const float* src = (t == 0 ? emb : feat) + ((size_t)c * NN + p * 16) * DD;
    int wave = threadIdx.x >> 6, lane = threadIdx.x & 63;
    int col = threadIdx.x * 4;    // this thread's 4 output columns

    __shared__ float sv[2][4][DD];   // 32 KB row double-buffer
    __shared__ float sinv[2][4];

    float4 v[4], vn[4];
    {
        const float* r0 = src + (size_t)wave * DD;
        #pragma unroll
        for (int k = 0; k < 4; ++k)
            v[k] = ntload4(r0 + k * 256 + lane * 4);
    }

    float4 acc = make_float4(0.f, 0.f, 0.f, 0.f);

    #pragma unroll
    for (int rnd = 0; rnd < 4; ++rnd) {
        int buf = rnd & 1;
        // stage this round's row to LDS; regs also feed local ss, then die
        #pragma unroll
        for (int k = 0; k < 4; ++k)
            *(float4*)&sv[buf][wave][k * 256 + lane * 4] = v[k];
        float ss = 0.f;
        #pragma unroll
        for (int k = 0; k < 4; ++k)
            ss += v[k].x * v[k].x + v[k].y * v[k].y +
                  v[k].z * v[k].z + v[k].w * v[k].w;

        // prefetch next round's row BEFORE the butterfly (nt: no L2 alloc)
        if (rnd < 3) {
            const float* rn = src + (size_t)((rnd + 1) * 4 + wave) * DD;
            #pragma unroll
            for (int k = 0; k < 4; ++k)
                vn[k] = ntload4(rn + k * 256 + lane * 4);
        }

        #pragma unroll
        for (int m = 32; m >= 1; m >>= 1)
            ss += __shfl_xor(ss, m, 64);
        if (lane == 0)
            sinv[buf][wave] = 1.0f / fmaxf(sqrtf(ss), 1e-12f);  // F.normalize eps
        __syncthreads();

        // consume from LDS: 4 b128 reads + broadcast scalars
        float i0 = sinv[buf][0], i1 = sinv[buf][1];
        float i2 = sinv[buf][2], i3 = sinv[buf][3];
        float4 u0 = *(float4*)&sv[buf][0][col];
        float4 u1 = *(float4*)&sv[buf][1][col];
        float4 u2 = *(float4*)&sv[buf][2][col];
        float4 u3 = *(float4*)&sv[buf][3][col];
        acc.x += u0.x * i0 + u1.x * i1 + u2.x * i2 + u3.x * i3;
        acc.y += u0.y * i0 + u1.y * i1 + u2.y * i2 + u3.y * i3;
        acc.z += u0.z * i0 + u1.z * i1 + u2.z * i2 + u3.z * i3;
        acc.w += u0.w * i0 + u1.w * i1 + u2.w * i2 + u3.w * i3;

        if (rnd < 3) {
            #pragma unroll
            for (int k = 0; k < 4; ++k) v[k] = vn[k];
        }
    }

    *(float4*)(parts + (((size_t)t * CC + c) * PARTS + p) * DD + col) = acc;
}

// ---------------- K3a: split-K tiled Gram partials (k2 fused) ---------
// grid = 2 tensors * 16 tiles(64x64) * 8 K-splits = 256 blocks, 256 thr.
// Stages directly from parts: mean = (sum of 4 parts) / N at load time.
__global__ __launch_bounds__(256) void k3a_gram(
    const float* __restrict__ parts, float* __restrict__ gpart /* [2][8][CC][CC] */)
{
    __shared__ float As[64][132];
    __shared__ float Bs[TK][68];

    int b = blockIdx.x;
    int t = b >> 7;
    int r = b & 127;
    int ks = r >> 4;
    int ti = (r >> 2) & 3, tj = r & 3;
    int i0 = ti * 64, j0 = tj * 64, k0 = ks * TK;
    const float invN = 1.0f / (float)NN;

    for (int f = threadIdx.x; f < 64 * 32; f += 256) {
        int row = f >> 5, c4 = f & 31;
        const float* P = parts + ((size_t)(t * CC + i0 + row) * PARTS) * DD + k0 + c4 * 4;
        float4 v0 = *(const float4*)(P);
        float4 v1 = *(const float4*)(P + DD);
        float4 v2 = *(const float4*)(P + 2 * DD);
        float4 v3 = *(const float4*)(P + 3 * DD);
        float4 v = make_float4((v0.x + v1.x + v2.x + v3.x) * invN,
                               (v0.y + v1.y + v2.y + v3.y) * invN,
                               (v0.z + v1.z + v2.z + v3.z) * invN,
                               (v0.w + v1.w + v2.w + v3.w) * invN);
        *(float4*)&As[row][c4 * 4] = v;
    }
    for (int f = threadIdx.x; f < 64 * 32; f += 256) {
        int row = f >> 5, c4 = f & 31;
        const float* P = parts + ((size_t)(t * CC + j0 + row) * PARTS) * DD + k0 + c4 * 4;
        float4 v0 = *(const float4*)(P);
        float4 v1 = *(const float4*)(P + DD);
        float4 v2 = *(const float4*)(P + 2 * DD);
        float4 v3 = *(const float4*)(P + 3 * DD);
        Bs[c4 * 4 + 0][row] = (v0.x + v1.x + v2.x + v3.x) * invN;
        Bs[c4 * 4 + 1][row] = (v0.y + v1.y + v2.y + v3.y) * invN;
        Bs[c4 * 4 + 2][row] = (v0.z + v1.z + v2.z + v3.z) * invN;
        Bs[c4 * 4 + 3][row] = (v0.w + v1.w + v2.w + v3.w) * invN;
    }
    __syncthreads();

    int tr = threadIdx.x >> 4, tc = threadIdx.x & 15;
    float acc[4][4] = {};
    #pragma unroll 4
    for (int kk = 0; kk < TK; kk += 4) {
        float4 a[4], bb[4];
        #pragma unroll
        for (int q = 0; q < 4; ++q) a[q] = *(float4*)&As[tr * 4 + q][kk];
        #pragma unroll
        for (int kq = 0; kq < 4; ++kq) bb[kq] = *(float4*)&Bs[kk + kq][tc * 4];
        #pragma unroll
        for (int q = 0; q < 4; ++q) {
            acc[q][0] += a[q].x * bb[0].x + a[q].y * bb[1].x + a[q].z * bb[2].x + a[q].w * bb[3].x;
            acc[q][1] += a[q].x * bb[0].y + a[q].y * bb[1].y + a[q].z * bb[2].y + a[q].w * bb[3].y;
            acc[q][2] += a[q].x * bb[0].z + a[q].y * bb[1].z + a[q].z * bb[2].z + a[q].w * bb[3].z;
            acc[q][3] += a[q].x * bb[0].w + a[q].y * bb[1].w + a[q].z * bb[2].w + a[q].w * bb[3].w;
        }
    }

    float* G = gpart + (((size_t)(t * 8 + ks) * CC) + i0 + tr * 4) * CC + j0 + tc * 4;
    #pragma unroll
    for (int q = 0; q < 4; ++q)
        *(float4*)(G + (size_t)q * CC) =
            make_float4(acc[q][0], acc[q][1], acc[q][2], acc[q][3]);
}

// ---------------- K3b: reduce partials + ListMLE + final mean ---------
// grid = CC blocks; one atomicAdd per block into out (zeroed by k1).
__global__ __launch_bounds__(256) void k3b_listmle(
    const float* __restrict__ gpart, float* __restrict__ out)
{
    int i = blockIdx.x, c = threadIdx.x;
    float dp = 0.f, dt = 0.f;
    #pragma unroll
    for (int ks = 0; ks < 8; ++ks) {
        dp += gpart[((size_t)ks * CC + i) * CC + c];
        dt += gpart[((size_t)(8 + ks) * CC + i) * CC + c];
    }

    __shared__ float s_true[CC];
    __shared__ float s_pexp[CC];
    s_true[c] = dt;
    s_pexp[c] = expf(dp);
    __syncthreads();

    // S = sum exp(pred_j) over j ranked at-or-after c (stable desc by true)
    float S = 0.f;
    for (int j = 0; j < CC; ++j) {
        float tj = s_true[j];
        bool take = (tj < dt) || (tj == dt && j >= c);
        S += take ? s_pexp[j] : 0.f;
    }
    float contrib = logf(S + 1e-10f) - dp;

    #pragma unroll
    for (int m = 32; m >= 1; m >>= 1)
        contrib += __shfl_xor(contrib, m, 64);
    __shared__ float s_red[4];
    if ((c & 63) == 0) s_red[c >> 6] = contrib;
    __syncthreads();
    if (c == 0)
        atomicAdd(out, (s_red[0] + s_red[1] + s_red[2] + s_red[3]) * (1.0f / (float)CC));
}

extern "C" void kernel_launch(void* const* d_in, const int* in_sizes, int n_in,
                              void* d_out, int out_size, void* d_ws, size_t ws_size,
                              hipStream_t stream) {
    const float* emb  = (const float*)d_in[0];
    const float* feat = (const float*)d_in[1];
    float* ws = (float*)d_ws;
    float* parts = ws;                                  // 2*CC*PARTS*DD = 8 MiB
    float* gpart = parts + (size_t)2 * CC * PARTS * DD; // 2*8*CC*CC = 4 MiB

    k1_partial <<<2 * CC * PARTS, 256, 0, stream>>>(emb, feat, parts, (float*)d_out);
    k3a_gram   <<<256, 256, 0, stream>>>(parts, gpart);
    k3b_listmle<<<CC, 256, 0, stream>>>(gpart, (float*)d_out);
}